// Round 14
// baseline (111.016 us; speedup 1.0000x reference)
//
#include <hip/hip_runtime.h>
#include <hip/hip_bf16.h>
#include <math.h>

#define B_ 4
#define T_ 4096
#define E_ 1024
#define H_ 64
#define NQT2 32      // T_/128 q-tiles (passA)
#define NCHA 8       // passA chunks of 512 keys
#define KCHA 512
#define TILESB3 272  // per-batch live causal (256q x 128k) tiles: sum 2(qt+1)
#define KFB (T_ * H_)   // shorts per batch in Kf/Vf (fragment-major)
#define PRJ_RS 1048  // LDS row stride in shorts (2096B): 2-way banks, 16B-aligned

using bf16x8 = __attribute__((ext_vector_type(8))) short;
using f32x4  = __attribute__((ext_vector_type(4))) float;

__device__ inline short f2bf_rn(float f) {
  return (short)((__builtin_bit_cast(unsigned, f) + 0x8000u) >> 16);
}
__device__ inline unsigned pack2(float a, float b) {
  const unsigned ua = __builtin_bit_cast(unsigned, a) + 0x8000u;
  const unsigned ub = __builtin_bit_cast(unsigned, b) + 0x8000u;
  return (ua >> 16) | (ub & 0xFFFF0000u);
}
__device__ inline float bf2f(short s) {
  unsigned u = ((unsigned)(unsigned short)s) << 16;
  return __builtin_bit_cast(float, u);
}

// ---------- wt fragment-major: wtf[n][ks][lane][8] = W[32ks+8g+e][(n&3)*16+l15]
__global__ __launch_bounds__(256)
void wtconv_kernel(const float* __restrict__ wq, const float* __restrict__ wk,
                   const float* __restrict__ wv, short* __restrict__ wtf) {
  const int t = threadIdx.x;
  const int lane = t & 63, g = lane >> 4, l15 = lane & 15;
  const int ks = (blockIdx.x & 7) * 4 + (t >> 6);
  const int n = blockIdx.x >> 3;           // 0..11
  const float* W = (n < 4) ? wq : (n < 8) ? wk : wv;
  const int h = (n & 3) * 16 + l15;
  const int kbase = 32 * ks + 8 * g;
  bf16x8 v;
#pragma unroll
  for (int e = 0; e < 8; ++e) v[e] = f2bf_rn(W[(size_t)(kbase + e) * H_ + h]);
  *(bf16x8*)&wtf[((size_t)(n * 32 + ks) * 64 + lane) * 8] = v;
}

// ---------- QKV projection v7: LDS-staged x, 32q block, 4 waves x 2 subtiles
__global__ __launch_bounds__(256)
void proj_kernel(const float* __restrict__ x, const short* __restrict__ wtf,
                 short* __restrict__ Qb, short* __restrict__ Kb,
                 short* __restrict__ Vt) {
  __shared__ short xs[32 * PRJ_RS];
  const int q0 = blockIdx.x * 32;
  const int t = threadIdx.x;
  {
    const float4* xsrc = (const float4*)(x + (size_t)q0 * E_);
#pragma unroll
    for (int j = 0; j < 32; ++j) {
      const int i = t + 256 * j;          // 8192 float4s total
      const int row = i >> 8, col4 = i & 255;
      const float4 v = xsrc[i];
      uint2 u;
      u.x = pack2(v.x, v.y);
      u.y = pack2(v.z, v.w);
      *(uint2*)&xs[row * PRJ_RS + col4 * 4] = u;
    }
  }
  __syncthreads();
  const int w = t >> 6, lane = t & 63, g = lane >> 4, l15 = lane & 15;
  f32x4 acc[6] = {{0,0,0,0},{0,0,0,0},{0,0,0,0},{0,0,0,0},{0,0,0,0},{0,0,0,0}};
  const short* xr0 = &xs[l15 * PRJ_RS + 8 * g];
  const short* xr1 = &xs[(16 + l15) * PRJ_RS + 8 * g];
#pragma unroll 4
  for (int ks = 0; ks < 32; ++ks) {
    const bf16x8 av0 = *(const bf16x8*)(xr0 + ks * 32);
    const bf16x8 av1 = *(const bf16x8*)(xr1 + ks * 32);
    const short* wp = wtf + ((size_t)(w * 3 * 32 + ks) * 64 + lane) * 8;
#pragma unroll
    for (int n = 0; n < 3; ++n) {
      const bf16x8 bfr = *(const bf16x8*)(wp + (size_t)n * 32 * 64 * 8);
      acc[n]     = __builtin_amdgcn_mfma_f32_16x16x32_bf16(av0, bfr, acc[n], 0, 0, 0);
      acc[3 + n] = __builtin_amdgcn_mfma_f32_16x16x32_bf16(av1, bfr, acc[3 + n], 0, 0, 0);
    }
  }
#pragma unroll
  for (int sub = 0; sub < 2; ++sub) {
#pragma unroll
    for (int n = 0; n < 3; ++n) {
      const int ntg = w * 3 + n;
      const int mat = ntg >> 2;
      const int h = (ntg & 3) * 16 + l15;
#pragma unroll
      for (int r = 0; r < 4; ++r) {
        const int q = q0 + sub * 16 + 4 * g + r;
        const short v = f2bf_rn(acc[3 * sub + n][r]);
        if (mat == 0)      Qb[(size_t)q * H_ + h] = v;
        else if (mat == 1) Kb[(size_t)q * H_ + h] = v;
        else               Vt[((size_t)(q >> 12) * H_ + h) * T_ + (q & (T_ - 1))] = v;
      }
    }
  }
}

// ---------- repack K,V into fragment-major Kf, Vf ----------
__global__ __launch_bounds__(256)
void repack_kernel(const short* __restrict__ Kb, const short* __restrict__ Vt,
                   short* __restrict__ Kf, short* __restrict__ Vf) {
  const int s = blockIdx.x, b = blockIdx.y;
  const int t = threadIdx.x;
  const int lane = t & 63, g = lane >> 4, l15 = lane & 15, slot = t >> 6;
  const int sig = ((l15 >> 2) << 3) + (l15 & 3);
  const size_t dst = ((size_t)b * KFB) + (((size_t)s * 4 + slot) * 64 + lane) * 8;
  const int key = 32 * s + sig + 4 * (slot >> 1);
  const int colK = (slot & 1) * 32 + 8 * g;
  *(bf16x8*)&Kf[dst] =
      *(const bf16x8*)&Kb[((size_t)b * T_ + key) * H_ + colK];
  *(bf16x8*)&Vf[dst] =
      *(const bf16x8*)&Vt[((size_t)b * H_ + slot * 16 + l15) * T_ + 32 * s + 8 * g];
}

// ---------- pass A: partial Z over a 512-key chunk, 128-q blocks ----------
__global__ __launch_bounds__(256, 4)
void passA_kernel(const short* __restrict__ Qb, const short* __restrict__ Kf,
                  float* __restrict__ Zp) {
  const int qt = blockIdx.x, c = blockIdx.y, b = blockIdx.z;
  const int t = threadIdx.x;
  const int w = t >> 6, lane = t & 63, g = lane >> 4, l15 = lane & 15;
  const int qbase = qt * 128 + w * 32;
  const short* Qp = Qb + (size_t)b * T_ * H_;
  const short* kfB = Kf + (size_t)b * KFB;
  bf16x8 aq[2][2];
#pragma unroll
  for (int qs = 0; qs < 2; ++qs)
#pragma unroll
    for (int h = 0; h < 2; ++h)
      aq[qs][h] = *(const bf16x8*)&Qp[(size_t)(qbase + qs*16 + l15) * H_ + h*32 + 8*g];
  float z0 = 0.f, z1 = 0.f;
  const int c0 = c * KCHA;
  for (int kt = c0; kt < c0 + KCHA; kt += 32) {
    const short* kbase = kfB + ((size_t)(kt >> 5) * 4) * 512 + (size_t)lane * 8;
    const bf16x8 ak00 = *(const bf16x8*)(kbase);
    const bf16x8 ak01 = *(const bf16x8*)(kbase + 512);
    const bf16x8 ak10 = *(const bf16x8*)(kbase + 1024);
    const bf16x8 ak11 = *(const bf16x8*)(kbase + 1536);
    f32x4 s00 = {0,0,0,0}, s01 = {0,0,0,0}, s10 = {0,0,0,0}, s11 = {0,0,0,0};
    s00 = __builtin_amdgcn_mfma_f32_16x16x32_bf16(ak00, aq[0][0], s00, 0,0,0);
    s00 = __builtin_amdgcn_mfma_f32_16x16x32_bf16(ak01, aq[0][1], s00, 0,0,0);
    s01 = __builtin_amdgcn_mfma_f32_16x16x32_bf16(ak10, aq[0][0], s01, 0,0,0);
    s01 = __builtin_amdgcn_mfma_f32_16x16x32_bf16(ak11, aq[0][1], s01, 0,0,0);
    s10 = __builtin_amdgcn_mfma_f32_16x16x32_bf16(ak00, aq[1][0], s10, 0,0,0);
    s10 = __builtin_amdgcn_mfma_f32_16x16x32_bf16(ak01, aq[1][1], s10, 0,0,0);
    s11 = __builtin_amdgcn_mfma_f32_16x16x32_bf16(ak10, aq[1][0], s11, 0,0,0);
    s11 = __builtin_amdgcn_mfma_f32_16x16x32_bf16(ak11, aq[1][1], s11, 0,0,0);
#pragma unroll
    for (int r = 0; r < 4; ++r) {
      z0 += __expf(s00[r] * 0.125f) + __expf(s01[r] * 0.125f);
      z1 += __expf(s10[r] * 0.125f) + __expf(s11[r] * 0.125f);
    }
  }
  z0 += __shfl_xor(z0, 16); z0 += __shfl_xor(z0, 32);
  z1 += __shfl_xor(z1, 16); z1 += __shfl_xor(z1, 32);
  if (lane < 16) {
    const size_t zb = ((size_t)(b * NQT2 + qt) * NCHA + c) * 128 + w * 32;
    Zp[zb + lane] = z0;
    Zp[zb + 16 + lane] = z1;
  }
}

// ---------- pass B v4: 256q x 128k tiles (1088 blocks), 64 q/wave, heavy-first
__global__ __launch_bounds__(256, 2)
void passB_kernel(const short* __restrict__ Qb, const short* __restrict__ Kf,
                  const short* __restrict__ Vf, const float* __restrict__ Zp,
                  short* __restrict__ po, float* __restrict__ pws) {
  const int b = blockIdx.y;
  const int f = TILESB3 - 1 - blockIdx.x;   // heavy (large qt) tiles first
  int qt = 0;
#pragma unroll
  for (int aa = 1; aa <= 15; ++aa) qt += (f >= aa * (aa + 1)) ? 1 : 0;
  const int c = f - qt * (qt + 1);          // 0..2qt+1
  const int q0 = qt * 256;
  const int c0 = c * 128;

  const int t = threadIdx.x;
  const int w = t >> 6, lane = t & 63, g = lane >> 4, l15 = lane & 15;
  const int qbase = q0 + w * 64;
  const short* Qp = Qb + (size_t)b * T_ * H_;
  const short* kfB = Kf + (size_t)b * KFB;
  const short* vfB = Vf + (size_t)b * KFB;

  bf16x8 aq[4][2];
#pragma unroll
  for (int qs = 0; qs < 4; ++qs)
#pragma unroll
    for (int h = 0; h < 2; ++h)
      aq[qs][h] = *(const bf16x8*)&Qp[(size_t)(qbase + qs*16 + l15) * H_ + h*32 + 8*g];

  float zinv[4];
#pragma unroll
  for (int qs = 0; qs < 4; ++qs) {
    const int gq = qbase + qs * 16 + l15;
    const int qt2 = gq >> 7, qr = gq & 127;
    float zt = 0.f;
#pragma unroll
    for (int cc = 0; cc < NCHA; ++cc)
      zt += Zp[((size_t)(b * NQT2 + qt2) * NCHA + cc) * 128 + qr];
    zinv[qs] = 1.0f / zt;
  }

  f32x4 o[4][4];
#pragma unroll
  for (int qs = 0; qs < 4; ++qs)
#pragma unroll
    for (int nt = 0; nt < 4; ++nt) o[qs][nt] = (f32x4){0.f, 0.f, 0.f, 0.f};
  float ws[4] = {0.f, 0.f, 0.f, 0.f};

  const int kend_w = min(c0 + 128, qbase + 64);
  for (int kt = c0; kt < kend_w; kt += 32) {
    const size_t sb = ((size_t)(kt >> 5) * 4) * 512 + (size_t)lane * 8;
    const short* kbase = kfB + sb;
    const bf16x8 ak00 = *(const bf16x8*)(kbase);
    const bf16x8 ak01 = *(const bf16x8*)(kbase + 512);
    const bf16x8 ak10 = *(const bf16x8*)(kbase + 1024);
    const bf16x8 ak11 = *(const bf16x8*)(kbase + 1536);
    f32x4 s0[4], s1[4];
#pragma unroll
    for (int qs = 0; qs < 4; ++qs) {
      f32x4 a = {0,0,0,0}, bq = {0,0,0,0};
      a  = __builtin_amdgcn_mfma_f32_16x16x32_bf16(ak00, aq[qs][0], a, 0,0,0);
      a  = __builtin_amdgcn_mfma_f32_16x16x32_bf16(ak01, aq[qs][1], a, 0,0,0);
      bq = __builtin_amdgcn_mfma_f32_16x16x32_bf16(ak10, aq[qs][0], bq, 0,0,0);
      bq = __builtin_amdgcn_mfma_f32_16x16x32_bf16(ak11, aq[qs][1], bq, 0,0,0);
      s0[qs] = a; s1[qs] = bq;
    }
    bf16x8 wb[4];
    if (kt + 31 <= qbase) {                 // interior: no mask
#pragma unroll
      for (int qs = 0; qs < 4; ++qs) {
        const float zi = zinv[qs];
        float wsl = 0.f;
#pragma unroll
        for (int r = 0; r < 4; ++r) {
          const float w0 = __expf(__expf(s0[qs][r] * 0.125f) * zi);
          const float w1 = __expf(__expf(s1[qs][r] * 0.125f) * zi);
          wsl += w0 + w1;
          wb[qs][r] = f2bf_rn(w0);
          wb[qs][4 + r] = f2bf_rn(w1);
        }
        ws[qs] += wsl;
      }
    } else {                                // diagonal: per-element mask
#pragma unroll
      for (int qs = 0; qs < 4; ++qs) {
        const int qg = qbase + qs * 16 + l15;
        const float zi = zinv[qs];
        float wsl = 0.f;
#pragma unroll
        for (int r = 0; r < 4; ++r) {
          const int key0 = kt + 8 * g + r;
          const float w0 = (key0     <= qg) ? __expf(__expf(s0[qs][r] * 0.125f) * zi) : 0.f;
          const float w1 = (key0 + 4 <= qg) ? __expf(__expf(s1[qs][r] * 0.125f) * zi) : 0.f;
          wsl += w0 + w1;
          wb[qs][r] = f2bf_rn(w0);
          wb[qs][4 + r] = f2bf_rn(w1);
        }
        ws[qs] += wsl;
      }
    }
    const short* vbase = vfB + sb;
#pragma unroll
    for (int nt = 0; nt < 4; ++nt) {
      const bf16x8 av = *(const bf16x8*)(vbase + nt * 512);
#pragma unroll
      for (int qs = 0; qs < 4; ++qs)
        o[qs][nt] = __builtin_amdgcn_mfma_f32_16x16x32_bf16(av, wb[qs], o[qs][nt], 0,0,0);
    }
  }

#pragma unroll
  for (int qs = 0; qs < 4; ++qs) {
    float v = ws[qs];
    v += __shfl_xor(v, 16);
    v += __shfl_xor(v, 32);
    ws[qs] = v;
  }

  const size_t base = ((size_t)b * TILESB3 + f) * 256;
#pragma unroll
  for (int qs = 0; qs < 4; ++qs) {
    const size_t row = base + w * 64 + qs * 16 + l15;
#pragma unroll
    for (int nt = 0; nt < 4; ++nt) {
      short4 v;
      v.x = f2bf_rn(o[qs][nt][0]); v.y = f2bf_rn(o[qs][nt][1]);
      v.z = f2bf_rn(o[qs][nt][2]); v.w = f2bf_rn(o[qs][nt][3]);
      *(short4*)&po[row * 64 + nt * 16 + 4 * g] = v;
    }
  }
  if (lane < 16) {
#pragma unroll
    for (int qs = 0; qs < 4; ++qs)
      pws[base + w * 64 + qs * 16 + lane] = ws[qs];
  }
}

// ---------- combine v3: 512 blocks (32 q-rows each), 2 items/thread ----------
__global__ __launch_bounds__(256)
void combine_kernel(const short* __restrict__ po, const float* __restrict__ pws,
                    float* __restrict__ out) {
  const int qb = blockIdx.x, b = blockIdx.y;   // qb: 0..127 (32-q granularity)
  const int qt = qb >> 3;                       // 256-q tile index 0..15
  const int qoff = (qb & 7) * 32;               // offset within tile
  const int basef = qt * (qt + 1);
  const int nc = 2 * qt + 2;
  const int t = threadIdx.x;
#pragma unroll
  for (int it = 0; it < 2; ++it) {
    const int e = t + it * 256;                 // 0..511: 32q x 16 d4
    const int q = e >> 4, d4 = e & 15;
    float ax = 0.f, ay = 0.f, az = 0.f, aw = 0.f, wsr = 0.f;
    for (int cc = 0; cc < nc; ++cc) {
      const size_t row = ((size_t)b * TILESB3 + basef + cc) * 256 + qoff + q;
      const short4 v = *(const short4*)&po[row * 64 + d4 * 4];
      ax += bf2f(v.x); ay += bf2f(v.y); az += bf2f(v.z); aw += bf2f(v.w);
      wsr += pws[row];
    }
    const float inv = 1.0f / wsr;
    float4 rv = make_float4(ax * inv, ay * inv, az * inv, aw * inv);
    *(float4*)&out[((size_t)(b * T_ + qt * 256 + qoff + q)) * H_ + d4 * 4] = rv;
  }
}

extern "C" void kernel_launch(void* const* d_in, const int* in_sizes, int n_in,
                              void* d_out, int out_size, void* d_ws, size_t ws_size,
                              hipStream_t stream) {
  (void)in_sizes; (void)n_in; (void)out_size; (void)ws_size;
  const float* x  = (const float*)d_in[0];
  const float* wq = (const float*)d_in[1];
  const float* wk = (const float*)d_in[2];
  const float* wv = (const float*)d_in[3];

  char* ws = (char*)d_ws;
  short* wtf = (short*)(ws);                       // 384 KB
  short* Qb  = (short*)(ws + 0x0060000);           // 2 MB
  short* Kb  = (short*)(ws + 0x0260000);           // 2 MB
  short* Vt  = (short*)(ws + 0x0460000);           // 2 MB
  short* Kf  = (short*)(ws + 0x0660000);           // 2 MB frag-major
  short* Vf  = (short*)(ws + 0x0860000);           // 2 MB frag-major
  float* Zp  = (float*)(ws + 0x0A60000);           // 512 KB
  float* pws = (float*)(ws + 0x0AE0000);           // 1.1 MB
  short* po  = (short*)(ws + 0x0C00000);           // 35.7 MB bf16
  float* outp = (float*)d_out;

  wtconv_kernel<<<96, 256, 0, stream>>>(wq, wk, wv, wtf);
  proj_kernel<<<(B_ * T_) / 32, 256, 0, stream>>>(x, wtf, Qb, Kb, Vt);
  repack_kernel<<<dim3(T_ / 32, B_), 256, 0, stream>>>(Kb, Vt, Kf, Vf);
  passA_kernel<<<dim3(NQT2, NCHA, B_), 256, 0, stream>>>(Qb, Kf, Zp);
  passB_kernel<<<dim3(TILESB3, B_), 256, 0, stream>>>(Qb, Kf, Vf, Zp, po, pws);
  combine_kernel<<<dim3(T_ / 32, B_), 256, 0, stream>>>(po, pws, outp);
}

// Round 15
// 95.240 us; speedup vs baseline: 1.1656x; 1.1656x over previous
//
#include <hip/hip_runtime.h>
#include <hip/hip_bf16.h>
#include <math.h>

#define B_ 4
#define T_ 4096
#define E_ 1024
#define H_ 64
#define KFB (T_ * H_)   // shorts per batch in Kf/Vf (fragment-major)
#define PRJ_RS 1048  // LDS row stride in shorts (2096B): 2-way banks, 16B-aligned

using bf16x8 = __attribute__((ext_vector_type(8))) short;
using f32x4  = __attribute__((ext_vector_type(4))) float;

__device__ inline short f2bf_rn(float f) {
  return (short)((__builtin_bit_cast(unsigned, f) + 0x8000u) >> 16);
}
__device__ inline unsigned pack2(float a, float b) {
  const unsigned ua = __builtin_bit_cast(unsigned, a) + 0x8000u;
  const unsigned ub = __builtin_bit_cast(unsigned, b) + 0x8000u;
  return (ua >> 16) | (ub & 0xFFFF0000u);
}
__device__ inline float bf2f(short s) {
  unsigned u = ((unsigned)(unsigned short)s) << 16;
  return __builtin_bit_cast(float, u);
}

// ---------- wt fragment-major: wtf[n][ks][lane][8] = W[32ks+8g+e][(n&3)*16+l15]
__global__ __launch_bounds__(256)
void wtconv_kernel(const float* __restrict__ wq, const float* __restrict__ wk,
                   const float* __restrict__ wv, short* __restrict__ wtf) {
  const int t = threadIdx.x;
  const int lane = t & 63, g = lane >> 4, l15 = lane & 15;
  const int ks = (blockIdx.x & 7) * 4 + (t >> 6);
  const int n = blockIdx.x >> 3;           // 0..11
  const float* W = (n < 4) ? wq : (n < 8) ? wk : wv;
  const int h = (n & 3) * 16 + l15;
  const int kbase = 32 * ks + 8 * g;
  bf16x8 v;
#pragma unroll
  for (int e = 0; e < 8; ++e) v[e] = f2bf_rn(W[(size_t)(kbase + e) * H_ + h]);
  *(bf16x8*)&wtf[((size_t)(n * 32 + ks) * 64 + lane) * 8] = v;
}

// ---------- QKV projection v7: LDS-staged x, 32q block, 4 waves x 2 subtiles
__global__ __launch_bounds__(256)
void proj_kernel(const float* __restrict__ x, const short* __restrict__ wtf,
                 short* __restrict__ Qb, short* __restrict__ Kb,
                 short* __restrict__ Vt) {
  __shared__ short xs[32 * PRJ_RS];
  const int q0 = blockIdx.x * 32;
  const int t = threadIdx.x;
  {
    const float4* xsrc = (const float4*)(x + (size_t)q0 * E_);
#pragma unroll
    for (int j = 0; j < 32; ++j) {
      const int i = t + 256 * j;          // 8192 float4s total
      const int row = i >> 8, col4 = i & 255;
      const float4 v = xsrc[i];
      uint2 u;
      u.x = pack2(v.x, v.y);
      u.y = pack2(v.z, v.w);
      *(uint2*)&xs[row * PRJ_RS + col4 * 4] = u;
    }
  }
  __syncthreads();
  const int w = t >> 6, lane = t & 63, g = lane >> 4, l15 = lane & 15;
  f32x4 acc[6] = {{0,0,0,0},{0,0,0,0},{0,0,0,0},{0,0,0,0},{0,0,0,0},{0,0,0,0}};
  const short* xr0 = &xs[l15 * PRJ_RS + 8 * g];
  const short* xr1 = &xs[(16 + l15) * PRJ_RS + 8 * g];
#pragma unroll 4
  for (int ks = 0; ks < 32; ++ks) {
    const bf16x8 av0 = *(const bf16x8*)(xr0 + ks * 32);
    const bf16x8 av1 = *(const bf16x8*)(xr1 + ks * 32);
    const short* wp = wtf + ((size_t)(w * 3 * 32 + ks) * 64 + lane) * 8;
#pragma unroll
    for (int n = 0; n < 3; ++n) {
      const bf16x8 bfr = *(const bf16x8*)(wp + (size_t)n * 32 * 64 * 8);
      acc[n]     = __builtin_amdgcn_mfma_f32_16x16x32_bf16(av0, bfr, acc[n], 0, 0, 0);
      acc[3 + n] = __builtin_amdgcn_mfma_f32_16x16x32_bf16(av1, bfr, acc[3 + n], 0, 0, 0);
    }
  }
#pragma unroll
  for (int sub = 0; sub < 2; ++sub) {
#pragma unroll
    for (int n = 0; n < 3; ++n) {
      const int ntg = w * 3 + n;
      const int mat = ntg >> 2;
      const int h = (ntg & 3) * 16 + l15;
#pragma unroll
      for (int r = 0; r < 4; ++r) {
        const int q = q0 + sub * 16 + 4 * g + r;
        const short v = f2bf_rn(acc[3 * sub + n][r]);
        if (mat == 0)      Qb[(size_t)q * H_ + h] = v;
        else if (mat == 1) Kb[(size_t)q * H_ + h] = v;
        else               Vt[((size_t)(q >> 12) * H_ + h) * T_ + (q & (T_ - 1))] = v;
      }
    }
  }
}

// ---------- repack K,V into fragment-major Kf, Vf ----------
__global__ __launch_bounds__(256)
void repack_kernel(const short* __restrict__ Kb, const short* __restrict__ Vt,
                   short* __restrict__ Kf, short* __restrict__ Vf) {
  const int s = blockIdx.x, b = blockIdx.y;
  const int t = threadIdx.x;
  const int lane = t & 63, g = lane >> 4, l15 = lane & 15, slot = t >> 6;
  const int sig = ((l15 >> 2) << 3) + (l15 & 3);
  const size_t dst = ((size_t)b * KFB) + (((size_t)s * 4 + slot) * 64 + lane) * 8;
  const int key = 32 * s + sig + 4 * (slot >> 1);
  const int colK = (slot & 1) * 32 + 8 * g;
  *(bf16x8*)&Kf[dst] =
      *(const bf16x8*)&Kb[((size_t)b * T_ + key) * H_ + colK];
  *(bf16x8*)&Vf[dst] =
      *(const bf16x8*)&Vt[((size_t)b * H_ + slot * 16 + l15) * T_ + 32 * s + 8 * g];
}

// ---------- fused attention: Z sweep + causal sweep, one block per 32-q band
// Block = 4 waves; wave w handles key chunks kt = w*32 + n*128 in BOTH phases.
// Phase 1: Z[q] over all T keys (uniform). LDS-reduce. Phase 2: causal
// w = exp(exp(s/8)/Z), PV accumulate. LDS-reduce across waves, write out fp32.
// No partials, no combine.
__global__ __launch_bounds__(256, 2)
void attn_fused_kernel(const short* __restrict__ Qb, const short* __restrict__ Kf,
                       const short* __restrict__ Vf, float* __restrict__ out) {
  __shared__ float osh[4][32][68];
  __shared__ float zsh[4][32];
  __shared__ float wsh[4][32];
  const int b = blockIdx.y;
  const int bx = blockIdx.x;
  // zig-zag: alternate heavy (large qt) and light bands for balance
  const int qt = (bx & 1) ? (bx >> 1) : (T_ / 32 - 1 - (bx >> 1));
  const int q0 = qt * 32;

  const int t = threadIdx.x;
  const int w = t >> 6, lane = t & 63, g = lane >> 4, l15 = lane & 15;
  const short* Qp = Qb + (size_t)b * T_ * H_;
  const short* kfB = Kf + (size_t)b * KFB;
  const short* vfB = Vf + (size_t)b * KFB;

  bf16x8 aq[2][2];
#pragma unroll
  for (int qs = 0; qs < 2; ++qs)
#pragma unroll
    for (int h = 0; h < 2; ++h)
      aq[qs][h] = *(const bf16x8*)&Qp[(size_t)(q0 + qs*16 + l15) * H_ + h*32 + 8*g];

  // ---- phase 1: Z over all keys, wave-interleaved chunks ----
  float z0 = 0.f, z1 = 0.f;
#pragma unroll 2
  for (int kt = w * 32; kt < T_; kt += 128) {
    const short* kbase = kfB + ((size_t)(kt >> 5) * 2048) + (size_t)lane * 8;
    const bf16x8 ak00 = *(const bf16x8*)(kbase);
    const bf16x8 ak01 = *(const bf16x8*)(kbase + 512);
    const bf16x8 ak10 = *(const bf16x8*)(kbase + 1024);
    const bf16x8 ak11 = *(const bf16x8*)(kbase + 1536);
    f32x4 s00 = {0,0,0,0}, s01 = {0,0,0,0}, s10 = {0,0,0,0}, s11 = {0,0,0,0};
    s00 = __builtin_amdgcn_mfma_f32_16x16x32_bf16(ak00, aq[0][0], s00, 0,0,0);
    s00 = __builtin_amdgcn_mfma_f32_16x16x32_bf16(ak01, aq[0][1], s00, 0,0,0);
    s01 = __builtin_amdgcn_mfma_f32_16x16x32_bf16(ak10, aq[0][0], s01, 0,0,0);
    s01 = __builtin_amdgcn_mfma_f32_16x16x32_bf16(ak11, aq[0][1], s01, 0,0,0);
    s10 = __builtin_amdgcn_mfma_f32_16x16x32_bf16(ak00, aq[1][0], s10, 0,0,0);
    s10 = __builtin_amdgcn_mfma_f32_16x16x32_bf16(ak01, aq[1][1], s10, 0,0,0);
    s11 = __builtin_amdgcn_mfma_f32_16x16x32_bf16(ak10, aq[1][0], s11, 0,0,0);
    s11 = __builtin_amdgcn_mfma_f32_16x16x32_bf16(ak11, aq[1][1], s11, 0,0,0);
#pragma unroll
    for (int r = 0; r < 4; ++r) {
      z0 += __expf(s00[r] * 0.125f) + __expf(s01[r] * 0.125f);
      z1 += __expf(s10[r] * 0.125f) + __expf(s11[r] * 0.125f);
    }
  }
  z0 += __shfl_xor(z0, 16); z0 += __shfl_xor(z0, 32);
  z1 += __shfl_xor(z1, 16); z1 += __shfl_xor(z1, 32);
  if (lane < 16) {
    zsh[w][lane] = z0;
    zsh[w][16 + lane] = z1;
  }
  __syncthreads();
  const float zinv0 =
      1.0f / (zsh[0][l15] + zsh[1][l15] + zsh[2][l15] + zsh[3][l15]);
  const float zinv1 =
      1.0f / (zsh[0][16 + l15] + zsh[1][16 + l15] + zsh[2][16 + l15] + zsh[3][16 + l15]);

  // ---- phase 2: causal keys, same interleave ----
  f32x4 o[2][4] = {{{0,0,0,0},{0,0,0,0},{0,0,0,0},{0,0,0,0}},
                   {{0,0,0,0},{0,0,0,0},{0,0,0,0},{0,0,0,0}}};
  float ws0 = 0.f, ws1 = 0.f;
  const int qg0 = q0 + l15, qg1 = q0 + 16 + l15;
#pragma unroll 2
  for (int kt = w * 32; kt < q0 + 32; kt += 128) {
    const size_t sb = ((size_t)(kt >> 5) * 2048) + (size_t)lane * 8;
    const short* kbase = kfB + sb;
    const bf16x8 ak00 = *(const bf16x8*)(kbase);
    const bf16x8 ak01 = *(const bf16x8*)(kbase + 512);
    const bf16x8 ak10 = *(const bf16x8*)(kbase + 1024);
    const bf16x8 ak11 = *(const bf16x8*)(kbase + 1536);
    f32x4 s00 = {0,0,0,0}, s01 = {0,0,0,0}, s10 = {0,0,0,0}, s11 = {0,0,0,0};
    s00 = __builtin_amdgcn_mfma_f32_16x16x32_bf16(ak00, aq[0][0], s00, 0,0,0);
    s00 = __builtin_amdgcn_mfma_f32_16x16x32_bf16(ak01, aq[0][1], s00, 0,0,0);
    s01 = __builtin_amdgcn_mfma_f32_16x16x32_bf16(ak10, aq[0][0], s01, 0,0,0);
    s01 = __builtin_amdgcn_mfma_f32_16x16x32_bf16(ak11, aq[0][1], s01, 0,0,0);
    s10 = __builtin_amdgcn_mfma_f32_16x16x32_bf16(ak00, aq[1][0], s10, 0,0,0);
    s10 = __builtin_amdgcn_mfma_f32_16x16x32_bf16(ak01, aq[1][1], s10, 0,0,0);
    s11 = __builtin_amdgcn_mfma_f32_16x16x32_bf16(ak10, aq[1][0], s11, 0,0,0);
    s11 = __builtin_amdgcn_mfma_f32_16x16x32_bf16(ak11, aq[1][1], s11, 0,0,0);
    bf16x8 wb0, wb1;
    if (kt + 31 <= q0) {                   // interior: all keys <= all q
#pragma unroll
      for (int r = 0; r < 4; ++r) {
        const float w0 = __expf(__expf(s00[r] * 0.125f) * zinv0);
        const float w1 = __expf(__expf(s01[r] * 0.125f) * zinv0);
        ws0 += w0 + w1; wb0[r] = f2bf_rn(w0); wb0[4 + r] = f2bf_rn(w1);
        const float w2 = __expf(__expf(s10[r] * 0.125f) * zinv1);
        const float w3 = __expf(__expf(s11[r] * 0.125f) * zinv1);
        ws1 += w2 + w3; wb1[r] = f2bf_rn(w2); wb1[4 + r] = f2bf_rn(w3);
      }
    } else {                                // diagonal: per-element mask
#pragma unroll
      for (int r = 0; r < 4; ++r) {
        const int key0 = kt + 8 * g + r;
        const float w0 = (key0     <= qg0) ? __expf(__expf(s00[r] * 0.125f) * zinv0) : 0.f;
        const float w1 = (key0 + 4 <= qg0) ? __expf(__expf(s01[r] * 0.125f) * zinv0) : 0.f;
        ws0 += w0 + w1; wb0[r] = f2bf_rn(w0); wb0[4 + r] = f2bf_rn(w1);
        const float w2 = (key0     <= qg1) ? __expf(__expf(s10[r] * 0.125f) * zinv1) : 0.f;
        const float w3 = (key0 + 4 <= qg1) ? __expf(__expf(s11[r] * 0.125f) * zinv1) : 0.f;
        ws1 += w2 + w3; wb1[r] = f2bf_rn(w2); wb1[4 + r] = f2bf_rn(w3);
      }
    }
    const short* vbase = vfB + sb;
#pragma unroll
    for (int nt = 0; nt < 4; ++nt) {
      const bf16x8 av = *(const bf16x8*)(vbase + nt * 512);
      o[0][nt] = __builtin_amdgcn_mfma_f32_16x16x32_bf16(av, wb0, o[0][nt], 0,0,0);
      o[1][nt] = __builtin_amdgcn_mfma_f32_16x16x32_bf16(av, wb1, o[1][nt], 0,0,0);
    }
  }

  ws0 += __shfl_xor(ws0, 16); ws0 += __shfl_xor(ws0, 32);
  ws1 += __shfl_xor(ws1, 16); ws1 += __shfl_xor(ws1, 32);
  if (lane < 16) {
    wsh[w][lane] = ws0;
    wsh[w][16 + lane] = ws1;
  }
#pragma unroll
  for (int qs = 0; qs < 2; ++qs)
#pragma unroll
    for (int nt = 0; nt < 4; ++nt)
      *(float4*)&osh[w][qs * 16 + l15][nt * 16 + 4 * g] =
          *(const float4*)&o[qs][nt];
  __syncthreads();

  // ---- epilogue: sum 4 waves, divide, store fp32 (coalesced) ----
#pragma unroll
  for (int it = 0; it < 2; ++it) {
    const int e = t + it * 256;            // 0..511: 32q x 16 col4
    const int q = e >> 4, c4 = e & 15;
    float4 v0 = *(const float4*)&osh[0][q][c4 * 4];
    float4 v1 = *(const float4*)&osh[1][q][c4 * 4];
    float4 v2 = *(const float4*)&osh[2][q][c4 * 4];
    float4 v3 = *(const float4*)&osh[3][q][c4 * 4];
    const float wsr = wsh[0][q] + wsh[1][q] + wsh[2][q] + wsh[3][q];
    const float inv = 1.0f / wsr;
    float4 rv;
    rv.x = (v0.x + v1.x + v2.x + v3.x) * inv;
    rv.y = (v0.y + v1.y + v2.y + v3.y) * inv;
    rv.z = (v0.z + v1.z + v2.z + v3.z) * inv;
    rv.w = (v0.w + v1.w + v2.w + v3.w) * inv;
    *(float4*)&out[((size_t)(b * T_ + q0 + q)) * H_ + c4 * 4] = rv;
  }
}

extern "C" void kernel_launch(void* const* d_in, const int* in_sizes, int n_in,
                              void* d_out, int out_size, void* d_ws, size_t ws_size,
                              hipStream_t stream) {
  (void)in_sizes; (void)n_in; (void)out_size; (void)ws_size;
  const float* x  = (const float*)d_in[0];
  const float* wq = (const float*)d_in[1];
  const float* wk = (const float*)d_in[2];
  const float* wv = (const float*)d_in[3];

  char* ws = (char*)d_ws;
  short* wtf = (short*)(ws);                       // 384 KB
  short* Qb  = (short*)(ws + 0x0060000);           // 2 MB
  short* Kb  = (short*)(ws + 0x0260000);           // 2 MB
  short* Vt  = (short*)(ws + 0x0460000);           // 2 MB
  short* Kf  = (short*)(ws + 0x0660000);           // 2 MB frag-major
  short* Vf  = (short*)(ws + 0x0860000);           // 2 MB frag-major
  float* outp = (float*)d_out;

  wtconv_kernel<<<96, 256, 0, stream>>>(wq, wk, wv, wtf);
  proj_kernel<<<(B_ * T_) / 32, 256, 0, stream>>>(x, wtf, Qb, Kb, Vt);
  repack_kernel<<<dim3(T_ / 32, B_), 256, 0, stream>>>(Kb, Vt, Kf, Vf);
  attn_fused_kernel<<<dim3(T_ / 32, B_), 256, 0, stream>>>(Qb, Kf, Vf, outp);
}